// Round 13
// baseline (199.972 us; speedup 1.0000x reference)
//
#include <hip/hip_runtime.h>
#include <hip/hip_bf16.h>

#define NB 8
#define NS 4096
#define NE 2048
#define NL 64
#define NH 128
#define NM (NB*NS)

typedef unsigned short ushort_t;
typedef __attribute__((ext_vector_type(4))) float f32x4;
typedef __attribute__((ext_vector_type(8))) __bf16 bf16x8;
typedef __attribute__((ext_vector_type(8))) unsigned short u16x8;
typedef __attribute__((ext_vector_type(4))) unsigned short u16x4;
typedef __attribute__((ext_vector_type(4))) unsigned int u32x4;

// 128^-0.5 * log2(e): folded into absorbed-q weights so attn uses exp2 directly
#define SCALE2 0.1275174537f

__device__ __forceinline__ float fast_exp2(float x) {
    return __builtin_amdgcn_exp2f(x);   // v_exp_f32: D = 2^S0
}

__device__ __forceinline__ unsigned short f2bf(float f) {
    union { float f; unsigned u; } v; v.f = f;
    unsigned u = v.u + 0x7fffu + ((v.u >> 16) & 1u);
    return (unsigned short)(u >> 16);
}

__device__ __forceinline__ float bf2f(ushort_t u) {
    union { unsigned u; float f; } v; v.u = (unsigned)u << 16; return v.f;
}

// XOR swizzle for 128-byte-stride LDS tiles (G4)
__device__ __forceinline__ int swz(int row, int colbyte) {
    return (row * 128 + colbyte) ^ ((row & 7) << 4);
}

// Raw barrier: LDS visibility only — does NOT drain vmcnt (T4).
__device__ __forceinline__ void wg_barrier() {
    asm volatile("s_waitcnt lgkmcnt(0)" ::: "memory");
    __builtin_amdgcn_s_barrier();
    __builtin_amdgcn_sched_barrier(0);
}

// ---------------------------------------------------------------------------
// prep: WcatT[128][2048] bf16.  rows 0..63 = W_dkv, rows 64..127 = absorbed^T * SCALE2
// ---------------------------------------------------------------------------
__global__ __launch_bounds__(256) void prep_kernel(
    const float* __restrict__ Wdkv, const float* __restrict__ Wk,
    const float* __restrict__ Wq, ushort_t* __restrict__ WcatT)
{
    __shared__ float wk[128 * 64];
    const int t = threadIdx.x;
    for (int i = t; i < 128 * 64; i += 256) wk[i] = Wk[i];
    __syncthreads();
    const int e = blockIdx.x * 256 + t;
    const int l0 = blockIdx.y * 16;
    float acc[16];
    #pragma unroll
    for (int l = 0; l < 16; ++l) acc[l] = 0.f;
    for (int h = 0; h < 128; ++h) {
        float q = Wq[h * NE + e];
        #pragma unroll
        for (int l = 0; l < 16; ++l) acc[l] += q * wk[h * 64 + l0 + l];
    }
    for (int l = 0; l < 16; ++l) WcatT[(64 + l0 + l) * NE + e] = f2bf(acc[l] * SCALE2);
    for (int l = 0; l < 16; ++l) WcatT[(l0 + l) * NE + e] = f2bf(Wdkv[(l0 + l) * NE + e]);
}

// ---------------------------------------------------------------------------
// proj: Y[M,128] = x[M,2048] @ WcatT^T.  BM=64,BN=128,BK=64, 4 waves (2x2).
// Depth-2 ping-pong register prefetch + raw barriers.
// Epilogue: latent(f32) + k(bf16) + q(bf16) + kt = latent^T (identity MFMA).
// (Measured R11: ~50 us, ~90% of its 45 us HBM floor — frozen.)
// ---------------------------------------------------------------------------
__global__ __launch_bounds__(256) void proj_kernel(
    const float* __restrict__ x, const ushort_t* __restrict__ WcatT,
    float* __restrict__ latent_out, ushort_t* __restrict__ k_bf,
    ushort_t* __restrict__ q_bf, ushort_t* __restrict__ kt)
{
    __shared__ ushort_t As[2][64 * 64];
    __shared__ ushort_t Bs[2][128 * 64];
    const int tid = threadIdx.x;
    const int w = tid >> 6, lane = tid & 63, lg = lane >> 4, li = lane & 15;
    const int m0 = blockIdx.x * 64;
    const int wm = (w >> 1) * 32, wn = (w & 1) * 64;
    const int srow = tid >> 3, scol = tid & 7;

    f32x4 acc[2][4];
    #pragma unroll
    for (int i = 0; i < 2; ++i)
        #pragma unroll
        for (int j = 0; j < 4; ++j) acc[i][j] = f32x4{0.f, 0.f, 0.f, 0.f};

    f32x4 a0reg[2][2], a1reg[2][2];
    u16x8 b0reg[4], b1reg[4];

#define PLOAD(k0, AR, BR) do { \
    _Pragma("unroll") for (int p = 0; p < 2; ++p) { \
        const float* gp = x + (long)(m0 + srow + 32 * p) * NE + (k0) + scol * 8; \
        AR[p][0] = *reinterpret_cast<const f32x4*>(gp); \
        AR[p][1] = *reinterpret_cast<const f32x4*>(gp + 4); } \
    _Pragma("unroll") for (int p = 0; p < 4; ++p) \
        BR[p] = *reinterpret_cast<const u16x8*>(WcatT + (long)(srow + 32 * p) * NE + (k0) + scol * 8); \
} while (0)

#define PWRITE(AR, BR, buf) do { \
    _Pragma("unroll") for (int p = 0; p < 2; ++p) { \
        union { unsigned uw[4]; u16x8 v; } hu; \
        asm("v_cvt_pk_bf16_f32 %0, %1, %2" : "=v"(hu.uw[0]) : "v"(AR[p][0][0]), "v"(AR[p][0][1])); \
        asm("v_cvt_pk_bf16_f32 %0, %1, %2" : "=v"(hu.uw[1]) : "v"(AR[p][0][2]), "v"(AR[p][0][3])); \
        asm("v_cvt_pk_bf16_f32 %0, %1, %2" : "=v"(hu.uw[2]) : "v"(AR[p][1][0]), "v"(AR[p][1][1])); \
        asm("v_cvt_pk_bf16_f32 %0, %1, %2" : "=v"(hu.uw[3]) : "v"(AR[p][1][2]), "v"(AR[p][1][3])); \
        *reinterpret_cast<u16x8*>(reinterpret_cast<char*>(As[buf]) + swz(srow + 32 * p, scol * 16)) = hu.v; } \
    _Pragma("unroll") for (int p = 0; p < 4; ++p) \
        *reinterpret_cast<u16x8*>(reinterpret_cast<char*>(Bs[buf]) + swz(srow + 32 * p, scol * 16)) = BR[p]; \
} while (0)

    auto compute = [&](int buf) {
        #pragma unroll
        for (int c = 0; c < 2; ++c) {
            bf16x8 af[2], bfv[4];
            #pragma unroll
            for (int mf = 0; mf < 2; ++mf)
                af[mf] = *reinterpret_cast<const bf16x8*>(
                    reinterpret_cast<const char*>(As[buf]) + swz(wm + 16 * mf + li, c * 64 + lg * 16));
            #pragma unroll
            for (int nf = 0; nf < 4; ++nf)
                bfv[nf] = *reinterpret_cast<const bf16x8*>(
                    reinterpret_cast<const char*>(Bs[buf]) + swz(wn + 16 * nf + li, c * 64 + lg * 16));
            #pragma unroll
            for (int mf = 0; mf < 2; ++mf)
                #pragma unroll
                for (int nf = 0; nf < 4; ++nf)
                    acc[mf][nf] = __builtin_amdgcn_mfma_f32_16x16x32_bf16(
                        af[mf], bfv[nf], acc[mf][nf], 0, 0, 0);
        }
    };

    PLOAD(0, a0reg, b0reg);
    PLOAD(64, a1reg, b1reg);
    PWRITE(a0reg, b0reg, 0);
    wg_barrier();

    for (int ks = 0; ks < 32; ks += 2) {
        if (ks + 2 < 32) PLOAD((ks + 2) * 64, a0reg, b0reg);
        compute(0);
        PWRITE(a1reg, b1reg, 1);
        wg_barrier();
        if (ks + 3 < 32) PLOAD((ks + 3) * 64, a1reg, b1reg);
        compute(1);
        if (ks + 2 < 32) PWRITE(a0reg, b0reg, 0);
        wg_barrier();
    }

    const int b = m0 >> 12, s0 = m0 & 4095;
    #pragma unroll
    for (int mf = 0; mf < 2; ++mf) {
        #pragma unroll
        for (int nf = 0; nf < 4; ++nf) {
            int col = wn + 16 * nf + li;
            #pragma unroll
            for (int r = 0; r < 4; ++r) {
                int row = m0 + wm + 16 * mf + 4 * lg + r;
                float v = acc[mf][nf][r];
                if (wn == 0) {
                    latent_out[(long)row * NL + col] = v;
                    k_bf[(long)row * NL + col] = f2bf(v);
                    *reinterpret_cast<ushort_t*>(reinterpret_cast<char*>(As[0]) +
                        swz(wm + 16 * mf + 4 * lg + r, col * 2)) = f2bf(v);
                } else {
                    q_bf[(long)row * NL + (col - 64)] = f2bf(v);
                }
            }
        }
    }
    wg_barrier();
    // kt-GEMM: kt[l][s] = latent^T via A = identity fragment.
    union { u16x8 u; bf16x8 v; } iu;
    #pragma unroll
    for (int j = 0; j < 8; ++j)
        iu.u[j] = (lg == (li >> 3) + 2 * (w & 1) && (li & 7) == j)
                      ? (ushort_t)0x3F80 : (ushort_t)0;
    const int ckt = w >> 1;
    f32x4 ktacc[4];
    #pragma unroll
    for (int nf = 0; nf < 4; ++nf) {
        bf16x8 bfv = *reinterpret_cast<const bf16x8*>(
            reinterpret_cast<const char*>(As[0]) + swz(16 * nf + li, ckt * 64 + lg * 16));
        ktacc[nf] = __builtin_amdgcn_mfma_f32_16x16x32_bf16(
            iu.v, bfv, f32x4{0.f, 0.f, 0.f, 0.f}, 0, 0, 0);
    }
    #pragma unroll
    for (int nf = 0; nf < 4; ++nf)
        #pragma unroll
        for (int r = 0; r < 4; ++r)
            kt[(long)(b * 64 + 16 * w + 4 * lg + r) * NS + s0 + 16 * nf + li] =
                f2bf(ktacc[nf][r]);
}

// ---------------------------------------------------------------------------
// attn: WAVE-INDEPENDENT causal flash attention in latent space.
// 4096 wave-tasks = (quarter h = wave-id, batch b, 32-q tile t). Zero LDS,
// zero barriers in the main loop; everything in registers:
//  - QK A-frags: direct 16B loads from k_bf (fragment-contiguous)
//  - PV  B-frags: direct 2x8B loads from kt with the kv(j) mapping
//    kv = (j<4 ? 4lg+j : 16+4lg+j-4) — identical to the R9-validated
//    TWRITE permutation (derived by inverting its bit-shuffle)
// Quarter h processes 32-kv chunks {h, h+4, ...} <= t. Unnormalized partials
// (O~ bf16-packed, L, M) written per task; merge_kernel combines exactly.
// ---------------------------------------------------------------------------
__global__ __launch_bounds__(256, 3) void attn_kernel(
    const ushort_t* __restrict__ q_bf, const ushort_t* __restrict__ k_bf,
    const ushort_t* __restrict__ kt, unsigned* __restrict__ Opart,
    float* __restrict__ lpart, float* __restrict__ mpart)
{
    const int tid = threadIdx.x;
    const int w = tid >> 6, lane = tid & 63, lg = lane >> 4, li = lane & 15;
    const int j = blockIdx.x;
    const int t = 127 - (j >> 3);     // heavy tiles first
    const int b = j & 7;
    const int h = w;                   // KV quarter = wave id
    const int Q0 = t << 5;
    const int nch = (h <= t) ? ((t - h) >> 2) + 1 : 0;

    // Q fragments (B-operand): lane owns col q = Q0+16qb+li, k elems l
    bf16x8 qf[2][2];
    #pragma unroll
    for (int qb = 0; qb < 2; ++qb)
        #pragma unroll
        for (int c = 0; c < 2; ++c)
            qf[qb][c] = *reinterpret_cast<const bf16x8*>(
                q_bf + ((long)b * NS + Q0 + 16 * qb + li) * NL + c * 32 + lg * 8);

    float m_r[2], l_r[2];
    m_r[0] = m_r[1] = -1.0e30f;
    l_r[0] = l_r[1] = 0.f;
    f32x4 oacc[2][4];
    #pragma unroll
    for (int qb = 0; qb < 2; ++qb)
        #pragma unroll
        for (int n = 0; n < 4; ++n) oacc[qb][n] = f32x4{0.f, 0.f, 0.f, 0.f};

    union VB { u16x4 h4[2]; bf16x8 v; };
    bf16x8 kfA[2][2], kfB[2][2];
    VB vbA[4], vbB[4];

#define AKLOAD(ch, KF, VBv) do { \
    const int kv0_ = (ch) * 32; \
    _Pragma("unroll") for (int c = 0; c < 2; ++c) \
        _Pragma("unroll") for (int f = 0; f < 2; ++f) \
            KF[c][f] = *reinterpret_cast<const bf16x8*>( \
                k_bf + ((long)b * NS + kv0_ + 16 * f + li) * NL + c * 32 + lg * 8); \
    _Pragma("unroll") for (int n = 0; n < 4; ++n) { \
        const ushort_t* kp_ = kt + ((long)b * 64 + 16 * n + li) * NS + kv0_ + 4 * lg; \
        VBv[n].h4[0] = *reinterpret_cast<const u16x4*>(kp_); \
        VBv[n].h4[1] = *reinterpret_cast<const u16x4*>(kp_ + 16); \
    } \
} while (0)

    auto compute = [&](bf16x8 (&kf)[2][2], VB (&vb)[4], bool diag, int kv0) {
        f32x4 s[2][2];
        #pragma unroll
        for (int f = 0; f < 2; ++f)
            #pragma unroll
            for (int qb = 0; qb < 2; ++qb) s[f][qb] = f32x4{0.f, 0.f, 0.f, 0.f};
        __builtin_amdgcn_s_setprio(1);
        #pragma unroll
        for (int c = 0; c < 2; ++c)
            #pragma unroll
            for (int f = 0; f < 2; ++f)
                #pragma unroll
                for (int qb = 0; qb < 2; ++qb)
                    s[f][qb] = __builtin_amdgcn_mfma_f32_16x16x32_bf16(
                        kf[c][f], qf[qb][c], s[f][qb], 0, 0, 0);
        __builtin_amdgcn_s_setprio(0);
        if (diag) {
            #pragma unroll
            for (int f = 0; f < 2; ++f)
                #pragma unroll
                for (int qb = 0; qb < 2; ++qb)
                    #pragma unroll
                    for (int r = 0; r < 4; ++r) {
                        int kv_g = kv0 + 16 * f + 4 * lg + r;
                        int q_g = Q0 + 16 * qb + li;
                        if (kv_g > q_g) s[f][qb][r] = -3.0e38f;
                    }
        }
        float mx[2];
        #pragma unroll
        for (int qb = 0; qb < 2; ++qb) {
            float m0_ = fmaxf(fmaxf(s[0][qb][0], s[0][qb][1]), fmaxf(s[0][qb][2], s[0][qb][3]));
            float m1_ = fmaxf(fmaxf(s[1][qb][0], s[1][qb][1]), fmaxf(s[1][qb][2], s[1][qb][3]));
            mx[qb] = fmaxf(m0_, m1_);
        }
        bool ok = (mx[0] <= m_r[0] + 8.f) && (mx[1] <= m_r[1] + 8.f);
        if (!__all(ok)) {
            #pragma unroll
            for (int qb = 0; qb < 2; ++qb) {
                float mxf = fmaxf(mx[qb], __shfl_xor(mx[qb], 16));
                mxf = fmaxf(mxf, __shfl_xor(mxf, 32));
                float m_new = fmaxf(m_r[qb], mxf);
                float corr = fast_exp2(m_r[qb] - m_new);
                m_r[qb] = m_new;
                l_r[qb] *= corr;
                float corrO[4];
                #pragma unroll
                for (int r = 0; r < 4; ++r)
                    corrO[r] = __shfl(corr, (lane & 48) | (4 * lg + r));
                #pragma unroll
                for (int n = 0; n < 4; ++n)
                    #pragma unroll
                    for (int r = 0; r < 4; ++r) oacc[qb][n][r] *= corrO[r];
            }
        }
        #pragma unroll
        for (int qb = 0; qb < 2; ++qb) {
            float rs = 0.f;
            #pragma unroll
            for (int f = 0; f < 2; ++f)
                #pragma unroll
                for (int r = 0; r < 4; ++r) {
                    float pv = fast_exp2(s[f][qb][r] - m_r[qb]);
                    s[f][qb][r] = pv;
                    rs += pv;
                }
            l_r[qb] += rs;
        }
        __builtin_amdgcn_s_setprio(1);
        #pragma unroll
        for (int qb = 0; qb < 2; ++qb) {
            union { unsigned uw[4]; bf16x8 v; } pa;
            asm("v_cvt_pk_bf16_f32 %0, %1, %2" : "=v"(pa.uw[0]) : "v"(s[0][qb][0]), "v"(s[0][qb][1]));
            asm("v_cvt_pk_bf16_f32 %0, %1, %2" : "=v"(pa.uw[1]) : "v"(s[0][qb][2]), "v"(s[0][qb][3]));
            asm("v_cvt_pk_bf16_f32 %0, %1, %2" : "=v"(pa.uw[2]) : "v"(s[1][qb][0]), "v"(s[1][qb][1]));
            asm("v_cvt_pk_bf16_f32 %0, %1, %2" : "=v"(pa.uw[3]) : "v"(s[1][qb][2]), "v"(s[1][qb][3]));
            #pragma unroll
            for (int n = 0; n < 4; ++n)
                oacc[qb][n] = __builtin_amdgcn_mfma_f32_16x16x32_bf16(
                    pa.v, vb[n].v, oacc[qb][n], 0, 0, 0);
        }
        __builtin_amdgcn_s_setprio(0);
    };

    if (nch > 0) {
        AKLOAD(h, kfA, vbA);
        for (int i = 0; i < nch; i += 2) {
            if (i + 1 < nch) AKLOAD(h + 4 * (i + 1), kfB, vbB);
            compute(kfA, vbA, h + 4 * i == t, (h + 4 * i) * 32);
            if (i + 1 >= nch) break;
            if (i + 2 < nch) AKLOAD(h + 4 * (i + 2), kfA, vbA);
            compute(kfB, vbB, h + 4 * (i + 1) == t, (h + 4 * (i + 1)) * 32);
        }
    }

    // epilogue: reduce l over lane-copies; write unnormalized partials
    #pragma unroll
    for (int qb = 0; qb < 2; ++qb) {
        l_r[qb] += __shfl_xor(l_r[qb], 16);
        l_r[qb] += __shfl_xor(l_r[qb], 32);
    }
    const long P = ((long)(h * NB + b) << 7) + t;
    #pragma unroll
    for (int qb = 0; qb < 2; ++qb)
        #pragma unroll
        for (int r = 0; r < 4; ++r) {
            union { unsigned uw[2]; u16x4 v; } u;
            asm("v_cvt_pk_bf16_f32 %0, %1, %2" : "=v"(u.uw[0]) : "v"(oacc[qb][0][r]), "v"(oacc[qb][1][r]));
            asm("v_cvt_pk_bf16_f32 %0, %1, %2" : "=v"(u.uw[1]) : "v"(oacc[qb][2][r]), "v"(oacc[qb][3][r]));
            int q = 16 * qb + 4 * lg + r;
            *reinterpret_cast<u16x4*>(Opart + P * 1024 + q * 32 + li * 2) = u.v;
        }
    if (lg == 0) {
        #pragma unroll
        for (int qb = 0; qb < 2; ++qb) {
            lpart[P * 32 + 16 * qb + li] = l_r[qb];
            mpart[P * 32 + 16 * qb + li] = m_r[qb];
        }
    }
}

// ---------------------------------------------------------------------------
// merge: exact 4-quarter combine + Wv out-GEMM + transposed coalesced store.
// 1024 blocks = (t, b). Quarter weights 2^(m_h - M); denom = sum w_h L_h.
// ---------------------------------------------------------------------------
__global__ __launch_bounds__(256) void merge_kernel(
    const unsigned* __restrict__ Opart, const float* __restrict__ lpart,
    const float* __restrict__ mpart, const float* __restrict__ Wv,
    float* __restrict__ out)
{
    __shared__ __attribute__((aligned(16))) char smem[20992];
    ushort_t* Ms = (ushort_t*)smem;            // 4 KB: merged O_lat [32q][64l] swizzled
    ushort_t* Wvs = (ushort_t*)(smem + 4096);  // 16 KB: Wv bf16 [128dv][64l] swizzled
    float* Os = (float*)smem;                  // overlay after GEMM: [32q][132dv]
    const int blk = blockIdx.x;
    const int b = blk & 7, t = blk >> 3;
    const int Q0 = t << 5;
    const int tid = threadIdx.x;
    const int w = tid >> 6, lane = tid & 63, lg = lane >> 4, li = lane & 15;

    // merge the 4 quarter-partials -> Ms
    {
        const int q = tid >> 3, g = tid & 7;   // q row, u32 group of 4
        float l4[4], m4[4];
        #pragma unroll
        for (int hh = 0; hh < 4; ++hh) {
            const long P = ((long)(hh * NB + b) << 7) + t;
            l4[hh] = lpart[P * 32 + q];
            m4[hh] = mpart[P * 32 + q];
        }
        float M = fmaxf(fmaxf(m4[0], m4[1]), fmaxf(m4[2], m4[3]));
        float a[4], L = 0.f;
        #pragma unroll
        for (int hh = 0; hh < 4; ++hh) { a[hh] = fast_exp2(m4[hh] - M); L += a[hh] * l4[hh]; }
        float inv = 1.f / L;
        #pragma unroll
        for (int hh = 0; hh < 4; ++hh) a[hh] *= inv;
        float acc[8];
        #pragma unroll
        for (int k = 0; k < 8; ++k) acc[k] = 0.f;
        #pragma unroll
        for (int hh = 0; hh < 4; ++hh) {
            const long P = ((long)(hh * NB + b) << 7) + t;
            u32x4 v = *reinterpret_cast<const u32x4*>(Opart + P * 1024 + q * 32 + g * 4);
            #pragma unroll
            for (int k = 0; k < 4; ++k) {
                union { unsigned u; float f; } lo, hi;
                lo.u = v[k] << 16; hi.u = v[k] & 0xffff0000u;
                acc[2 * k]     += a[hh] * lo.f;
                acc[2 * k + 1] += a[hh] * hi.f;
            }
        }
        // u32 index u = g*4+k holds (dv_lo = 32*(u&1) + (u>>1), dv_hi = dv_lo+16)
        #pragma unroll
        for (int k = 0; k < 4; ++k) {
            int u = g * 4 + k;
            int li2 = u >> 1, p = u & 1;
            int dlo = 32 * p + li2, dhi = dlo + 16;
            *reinterpret_cast<ushort_t*>(reinterpret_cast<char*>(Ms) + swz(q, dlo * 2)) = f2bf(acc[2 * k]);
            *reinterpret_cast<ushort_t*>(reinterpret_cast<char*>(Ms) + swz(q, dhi * 2)) = f2bf(acc[2 * k + 1]);
        }
        // stage Wv (f32 -> bf16) -> Wvs: [128 dv][64 l], swizzled
        const int r = tid >> 1, hf = tid & 1;
        const float* wp = Wv + r * 64 + hf * 32;
        #pragma unroll
        for (int qq = 0; qq < 2; ++qq) {
            f32x4 w0 = *reinterpret_cast<const f32x4*>(wp + qq * 16);
            f32x4 w1 = *reinterpret_cast<const f32x4*>(wp + qq * 16 + 4);
            f32x4 w2 = *reinterpret_cast<const f32x4*>(wp + qq * 16 + 8);
            f32x4 w3 = *reinterpret_cast<const f32x4*>(wp + qq * 16 + 12);
            u16x8 h0, h1;
            #pragma unroll
            for (int jj = 0; jj < 4; ++jj) {
                h0[jj] = f2bf(w0[jj]); h0[4 + jj] = f2bf(w1[jj]);
                h1[jj] = f2bf(w2[jj]); h1[4 + jj] = f2bf(w3[jj]);
            }
            *reinterpret_cast<u16x8*>(reinterpret_cast<char*>(Wvs) + swz(r, hf * 64 + qq * 32)) = h0;
            *reinterpret_cast<u16x8*>(reinterpret_cast<char*>(Wvs) + swz(r, hf * 64 + qq * 32 + 16)) = h1;
        }
    }
    wg_barrier();

    // out-GEMM: D[dv][q] = Wv[dv][l] * Om^T[l][q]; wave w owns dv 32w..32w+31
    f32x4 vacc[2][2];
    #pragma unroll
    for (int i = 0; i < 2; ++i)
        #pragma unroll
        for (int jj = 0; jj < 2; ++jj) vacc[i][jj] = f32x4{0.f, 0.f, 0.f, 0.f};
    #pragma unroll
    for (int c = 0; c < 2; ++c) {
        bf16x8 af[2], bfv[2];
        #pragma unroll
        for (int mf = 0; mf < 2; ++mf)
            af[mf] = *reinterpret_cast<const bf16x8*>(
                reinterpret_cast<const char*>(Wvs) + swz(32 * w + 16 * mf + li, c * 64 + lg * 16));
        #pragma unroll
        for (int nf = 0; nf < 2; ++nf)
            bfv[nf] = *reinterpret_cast<const bf16x8*>(
                reinterpret_cast<const char*>(Ms) + swz(16 * nf + li, c * 64 + lg * 16));
        #pragma unroll
        for (int mf = 0; mf < 2; ++mf)
            #pragma unroll
            for (int nf = 0; nf < 2; ++nf)
                vacc[mf][nf] = __builtin_amdgcn_mfma_f32_16x16x32_bf16(
                    af[mf], bfv[nf], vacc[mf][nf], 0, 0, 0);
    }
    wg_barrier();
    // transpose-stage Os[q][dv] then coalesced f32x4 global writes
    #pragma unroll
    for (int mf = 0; mf < 2; ++mf)
        #pragma unroll
        for (int nf = 0; nf < 2; ++nf)
            #pragma unroll
            for (int r = 0; r < 4; ++r)
                Os[(16 * nf + li) * 132 + 32 * w + 16 * mf + 4 * lg + r] = vacc[mf][nf][r];
    wg_barrier();
    {
        const int r = tid >> 3, cb = (tid & 7) * 16;
        float* op = out + ((long)b * NS + Q0 + r) * NH + cb;
        const float* sp = Os + r * 132 + cb;
        #pragma unroll
        for (int qq = 0; qq < 4; ++qq)
            *reinterpret_cast<f32x4*>(op + 4 * qq) = *reinterpret_cast<const f32x4*>(sp + 4 * qq);
    }
}

// ---------------------------------------------------------------------------
extern "C" void kernel_launch(void* const* d_in, const int* in_sizes, int n_in,
                              void* d_out, int out_size, void* d_ws, size_t ws_size,
                              hipStream_t stream) {
    const float* x    = (const float*)d_in[0];
    const float* Wdkv = (const float*)d_in[1];
    const float* Wk   = (const float*)d_in[2];
    const float* Wv   = (const float*)d_in[3];
    const float* Wq   = (const float*)d_in[4];

    float* out = (float*)d_out;
    float* latent_out = out + (long)NM * NH;   // output 1 follows output 0

    // workspace (~30.3 MB)
    ushort_t* WcatT = (ushort_t*)d_ws;                 // 512 KB
    ushort_t* q_bf  = WcatT + 128 * NE;                // 4 MB
    ushort_t* k_bf  = q_bf + (long)NM * NL;            // 4 MB
    ushort_t* kt    = k_bf + (long)NM * NL;            // 4 MB (latent^T)
    unsigned* Opart = (unsigned*)(kt + (long)NM * NL); // 4096*1024 u32 = 16.8 MB
    float* lpart = (float*)(Opart + (long)4096 * 1024);// 512 KB
    float* mpart = lpart + 4096 * 32;                  // 512 KB

    hipLaunchKernelGGL(prep_kernel, dim3(NE / 256, 4), dim3(256), 0, stream, Wdkv, Wk, Wq, WcatT);
    hipLaunchKernelGGL(proj_kernel, dim3(NM / 64), dim3(256), 0, stream,
                       x, WcatT, latent_out, k_bf, q_bf, kt);
    hipLaunchKernelGGL(attn_kernel, dim3(1024), dim3(256), 0, stream,
                       q_bf, k_bf, kt, Opart, lpart, mpart);
    hipLaunchKernelGGL(merge_kernel, dim3(1024), dim3(256), 0, stream,
                       Opart, lpart, mpart, Wv, out);
}